// Round 3
// baseline (1556.471 us; speedup 1.0000x reference)
//
#include <hip/hip_runtime.h>
#include <hip/hip_bf16.h>

// DigitCaps routing, fused. Key identity: the routing logits are linear in v:
//   b_k[b,r,c] = u_hat[b,r,c,:] . (v_1+...+v_{k-1})[b,c,:]  (= uh . Vsum)
// so no [B,R,C] logit state is materialized; u_hat is recomputed per pass
// entirely in registers.
//
// Round-2 post-mortem: passes were 500us each at 5% VALU / 0.9% HBM --
// latency-bound on the global CAS-atomicAdd flush (64 blocks sweeping the
// same addresses in lockstep). Round-3 fix: NO global atomics -- each block
// stores its partial s to a private slab Pg[y][x][64][160]; a fused
// reduce+squash kernel sums the 64 x-partials (shfl-reduce for |s|^2).
// Pass-kernel main loop is byte-identical to round 2 for a clean A/B.

#define NBATCH 512
#define NR     1152
#define NCLS   10
#define NOUT   16
#define RCHUNK 18          // r-rows per block; grid.x = 1152/18 = 64
#define NPX    64          // grid.x (number of r-partials)
#define CO     160         // NCLS*NOUT

__device__ __forceinline__ unsigned short f2bf_rne(float x) {
    unsigned u = __float_as_uint(x);
    return (unsigned short)((u + 0x7fffu + ((u >> 16) & 1u)) >> 16);
}

template<bool FIRST>
__global__ __launch_bounds__(256, 2)
void caps_pass(const float* __restrict__ U, const float* __restrict__ W,
               const float* __restrict__ Vsum, float* __restrict__ Pg)
{
    // stride 161 floats (odd) -> lane b and b+32 share a bank: 2-way = free
    __shared__ float s_part[64][161];            // 41.2 KB partial s, lane-owned rows
    __shared__ unsigned short vs_l[64][162];     // 20.7 KB bf16 Vsum (stride 81 dwords, odd)

    const int tid  = threadIdx.x;
    const int lane = tid & 63;
    const int b0   = ((int)blockIdx.y) << 6;     // 64 batches per block, lane = batch

    for (int idx = tid; idx < 64 * 161; idx += 256)
        (&s_part[0][0])[idx] = 0.0f;
    if (!FIRST) {
        for (int idx = tid; idx < 64 * CO; idx += 256) {
            int bl = idx / CO;
            int m  = idx - bl * CO;
            vs_l[bl][m] = f2bf_rne(Vsum[(size_t)(b0 + bl) * CO + m]);
        }
    }
    __syncthreads();

    // wave id forced to SGPR so r (and all W addresses) are provably uniform
    const int wv    = __builtin_amdgcn_readfirstlane(tid >> 6);
    const int rbase = (int)blockIdx.x * RCHUNK;
    const size_t ubase = (size_t)(b0 + lane) * (NR * 8);

    for (int r = rbase + wv; r < rbase + RCHUNK; r += 4) {
        const float4* up = reinterpret_cast<const float4*>(U + ubase + (size_t)r * 8);
        float4 u0 = up[0], u1 = up[1];
        const float uu[8] = {u0.x,u0.y,u0.z,u0.w, u1.x,u1.y,u1.z,u1.w};

        const float* wr = W + (size_t)r * (NCLS * 128);   // W[r][c][i][o]

        float uh[NCLS][NOUT];                    // all indexing static
        #pragma unroll
        for (int c = 0; c < NCLS; ++c) {
            #pragma unroll
            for (int o = 0; o < NOUT; ++o) uh[c][o] = 0.0f;
            #pragma unroll
            for (int i = 0; i < 8; ++i) {
                const float4* wp = reinterpret_cast<const float4*>(wr + c * 128 + i * 16);
                float4 w0 = wp[0], w1 = wp[1], w2 = wp[2], w3 = wp[3];
                const float wf[16] = {w0.x,w0.y,w0.z,w0.w, w1.x,w1.y,w1.z,w1.w,
                                      w2.x,w2.y,w2.z,w2.w, w3.x,w3.y,w3.z,w3.w};
                const float ui = uu[i];
                #pragma unroll
                for (int o = 0; o < NOUT; ++o)
                    uh[c][o] = __builtin_fmaf(ui, wf[o], uh[c][o]);
            }
        }

        float coef[NCLS];
        if (FIRST) {
            // Vsum == 0 -> logits 0 -> softmax uniform
            #pragma unroll
            for (int c = 0; c < NCLS; ++c) coef[c] = 0.1f;
        } else {
            float lg[NCLS];
            #pragma unroll
            for (int c = 0; c < NCLS; ++c) {
                float acc = 0.0f;
                #pragma unroll
                for (int o2 = 0; o2 < 8; ++o2) {
                    const unsigned pv =
                        *reinterpret_cast<const unsigned*>(&vs_l[lane][c * 16 + o2 * 2]);
                    acc = __builtin_fmaf(uh[c][o2*2],     __uint_as_float(pv << 16), acc);
                    acc = __builtin_fmaf(uh[c][o2*2 + 1], __uint_as_float(pv & 0xffff0000u), acc);
                }
                lg[c] = acc;
            }
            float mx = lg[0];
            #pragma unroll
            for (int c = 1; c < NCLS; ++c) mx = fmaxf(mx, lg[c]);
            float den = 0.0f;
            #pragma unroll
            for (int c = 0; c < NCLS; ++c) { float e = __expf(lg[c] - mx); coef[c] = e; den += e; }
            const float inv = 1.0f / den;
            #pragma unroll
            for (int c = 0; c < NCLS; ++c) coef[c] *= inv;
        }

        // lane-exclusive rows within a wave; atomic only vs the other 3 waves
        // (LDS ds_add_f32, fire-and-forget)
        #pragma unroll
        for (int c = 0; c < NCLS; ++c) {
            const float cc = coef[c];
            #pragma unroll
            for (int o = 0; o < NOUT; ++o)
                atomicAdd(&s_part[lane][c * 16 + o], cc * uh[c][o]);
        }
    }

    __syncthreads();

    // plain coalesced store of this block's partial: Pg[y][x][bl][m]
    float* pg = Pg + (size_t)((int)blockIdx.y * NPX + (int)blockIdx.x) * (64 * CO);
    for (int idx = tid; idx < 64 * CO; idx += 256) {
        int bl = idx / CO;
        int m  = idx - bl * CO;
        pg[idx] = s_part[bl][m];
    }
}

// Sums the 64 x-partials per (b,c,o), then squash. mode: 0 = write Vsum,
// 1 = Vsum += v, 2 = write final output.
__global__ __launch_bounds__(256)
void caps_reduce_squash(const float* __restrict__ Pg, float* __restrict__ Vsum,
                        float* __restrict__ out, const int mode)
{
    const int g = (int)blockIdx.x * 256 + threadIdx.x;   // [0, 81920), exact
    const int b = g / CO;
    const int m = g - b * CO;
    const int y = b >> 6, bl = b & 63;

    const float* p = Pg + ((size_t)(y * NPX) * 64 + bl) * CO + m;
    float s = 0.0f;
    #pragma unroll 16
    for (int x = 0; x < NPX; ++x)
        s += p[(size_t)x * (64 * CO)];

    // 16 lanes of one (b,c) are contiguous and 16-aligned within the wave
    // (group start = b*160 + c*16 ≡ 0 mod 16)
    float ss = s * s;
    ss += __shfl_xor(ss, 1);
    ss += __shfl_xor(ss, 2);
    ss += __shfl_xor(ss, 4);
    ss += __shfl_xor(ss, 8);
    const float f = sqrtf(ss) / (1.0f + ss);   // |s|/(1+|s|^2)
    const float v = f * s;

    if (mode == 2)      out[g] = v;
    else if (mode == 0) Vsum[g] = v;
    else                Vsum[g] += v;
}

extern "C" void kernel_launch(void* const* d_in, const int* in_sizes, int n_in,
                              void* d_out, int out_size, void* d_ws, size_t ws_size,
                              hipStream_t stream)
{
    (void)in_sizes; (void)n_in; (void)out_size; (void)ws_size;
    const float* U = (const float*)d_in[0];         // [512][1152][8] f32
    const float* W = (const float*)d_in[1];         // [1][1152][10][8][16] f32
    float* Pg   = (float*)d_ws;                     // [8][64][64][160] f32 = 21 MB
    float* Vsum = Pg + (size_t)NBATCH * NPX * CO;   // [512][10][16] f32
    float* out  = (float*)d_out;                    // [512][10][16] f32

    dim3 grid(NR / RCHUNK, NBATCH / 64);            // (64, 8) = 512 blocks
    dim3 blk(256);
    dim3 rgrid((NBATCH * CO) / 256);                // 320 blocks, exact

    caps_pass<true ><<<grid, blk, 0, stream>>>(U, W, nullptr, Pg);
    caps_reduce_squash<<<rgrid, blk, 0, stream>>>(Pg, Vsum, nullptr, 0);
    caps_pass<false><<<grid, blk, 0, stream>>>(U, W, Vsum, Pg);
    caps_reduce_squash<<<rgrid, blk, 0, stream>>>(Pg, Vsum, nullptr, 1);
    caps_pass<false><<<grid, blk, 0, stream>>>(U, W, Vsum, Pg);
    caps_reduce_squash<<<rgrid, blk, 0, stream>>>(Pg, Vsum, out, 2);
}